// Round 5
// baseline (173.953 us; speedup 1.0000x reference)
//
#include <hip/hip_runtime.h>
#include <hip/hip_bf16.h>

// Problem constants (fixed by the reference): B=4, H=16, S=1024, D=64.
#define B_N 4
#define H_N 16
#define S_N 1024
#define D_N 64
#define NELEM (B_N * H_N * S_N * D_N)   // 4194304 elements per tensor

typedef __bf16 bf16;
typedef bf16  bf16x4 __attribute__((ext_vector_type(4)));
typedef bf16  bf16x8 __attribute__((ext_vector_type(8)));
typedef float f32x4  __attribute__((ext_vector_type(4)));
typedef unsigned int u32x2 __attribute__((ext_vector_type(2)));

#define AS1 __attribute__((address_space(1)))
#define AS3 __attribute__((address_space(3)))
// global->LDS DMA, 16B per lane; LDS dest = wave-uniform base + lane*16 (m104)
#define GLL16(gp, lp) __builtin_amdgcn_global_load_lds((const AS1 void*)(gp), (AS3 void*)(lp), 16, 0, 0)

// ============================================================================
// Prep: fp32 -> bf16 with swizzled layouts, into d_ws.
//  Qb[bh][q][d]      linear, pre-scaled by 1/sqrt(64)
//  Kb[bh][k][d]      16B slots within each 128B row XORed by (k&7)
//  Vt[bh][d][k]      transposed; within each 64-k chunk, slots XORed by (d&7)
// ============================================================================
__global__ __launch_bounds__(256)
void prep_qk(const float* __restrict__ Q, const float* __restrict__ K,
             bf16* __restrict__ Qb, bf16* __restrict__ Kb)
{
    int t = blockIdx.x * 256 + threadIdx.x;
    const int half = NELEM / 8;            // threads per tensor (8 elems each)
    bool isQ = t < half;
    int tt = isQ ? t : t - half;
    int row = tt >> 3, sub = tt & 7;       // row: global (bh*S + s); sub: 16B slot
    const float* src = (isQ ? Q : K) + (size_t)row * 64 + sub * 8;
    float4 f0 = *(const float4*)src;
    float4 f1 = *(const float4*)(src + 4);
    float s = isQ ? 0.125f : 1.0f;
    bf16x8 o;
    o[0] = (bf16)(f0.x * s); o[1] = (bf16)(f0.y * s);
    o[2] = (bf16)(f0.z * s); o[3] = (bf16)(f0.w * s);
    o[4] = (bf16)(f1.x * s); o[5] = (bf16)(f1.y * s);
    o[6] = (bf16)(f1.z * s); o[7] = (bf16)(f1.w * s);
    int slot = isQ ? sub : (sub ^ (row & 7));
    bf16* dst = (isQ ? Qb : Kb) + (size_t)row * 64 + slot * 8;
    *(bf16x8*)dst = o;
}

__global__ __launch_bounds__(256)
void prep_v(const float* __restrict__ V, bf16* __restrict__ Vt)
{
    // One wave per (bh, 8-k chunk): lane = d. Reads are 256B-coalesced rows.
    int wid  = blockIdx.x * 4 + (threadIdx.x >> 6);
    int lane = threadIdx.x & 63;
    int bh = wid >> 7, chunk = wid & 127;          // 128 chunks of 8 k-rows
    const float* src = V + (size_t)bh * S_N * D_N + (size_t)chunk * 8 * 64 + lane;
    bf16x8 o;
#pragma unroll
    for (int j = 0; j < 8; ++j) o[j] = (bf16)src[j * 64];
    int slot = (chunk & 7) ^ (lane & 7);           // swizzle within 64-k chunk
    bf16* dst = Vt + (size_t)bh * D_N * S_N + (size_t)lane * S_N
                   + (chunk >> 3) * 64 + slot * 8;
    *(bf16x8*)dst = o;
}

// ============================================================================
// Main fused kernel: 1 block = 64 q-rows (4 waves x 16), two passes over K.
// Round 5: round-4 skeleton + NON-TEMPORAL P/O stores (no L2 write-allocate;
// K/V stay L2-resident, store stream goes straight to HBM).
// ============================================================================
__global__ __launch_bounds__(256)
void sdpa_main(const bf16* __restrict__ Qb, const bf16* __restrict__ Kb,
               const bf16* __restrict__ Vt, float* __restrict__ Og,
               float* __restrict__ Pg)
{
    // 128B alignment: tr_read regions are 128B-aligned (slot-select semantics)
    __shared__ __attribute__((aligned(128))) bf16 K_lds[2][4096];   // 16KB
    __shared__ __attribute__((aligned(128))) bf16 V_lds[2][4096];   // 16KB
    __shared__ __attribute__((aligned(128))) bf16 Pt_lds[4][1024];  // 8KB

    // XCD-bijective swizzle: 16 q-tiles of each bh land on one XCD (nwg=1024%8==0)
    const int bid = blockIdx.x;
    const int swz = (bid & 7) * 128 + (bid >> 3);
    const int bh = swz >> 4, qtile = swz & 15;

    const int tid = threadIdx.x;
    const int wave = tid >> 6, lane = tid & 63;
    const int l16 = lane & 15, lgrp = lane >> 4;
    const int swx = (l16 & 7) << 4;     // byte XOR for swizzled LDS reads

    const bf16* Qp = Qb + (size_t)bh * S_N * D_N;
    const bf16* Kp = Kb + (size_t)bh * S_N * D_N;
    const bf16* Vp = Vt + (size_t)bh * D_N * S_N;
    float* Op = Og + (size_t)bh * S_N * D_N;
    float* Pp = Pg + (size_t)bh * S_N * S_N;

    // Q A-fragments (already bf16 + scaled): a[j] = Q[q=l16-row][k=lgrp*8+j]
    const int qrow = qtile * 64 + wave * 16 + l16;
    bf16x8 aq[2];
    aq[0] = *(const bf16x8*)(Qp + (size_t)qrow * 64 + lgrp * 8);
    aq[1] = *(const bf16x8*)(Qp + (size_t)qrow * 64 + 32 + lgrp * 8);

    // Staging helpers: one 64x64 bf16 tile = 8KB = 2 GLL16 per wave (4 waves)
    auto stage_k = [&](int kt, int buf) {
        const bf16* gk = Kp + (size_t)kt * 64;
        GLL16(gk + (wave    ) * 512 + lane * 8, &K_lds[buf][(wave    ) * 512]);
        GLL16(gk + (wave + 4) * 512 + lane * 8, &K_lds[buf][(wave + 4) * 512]);
    };
    auto stage_v = [&](int kt, int buf) {
        const int dr = lane >> 3, c7 = lane & 7;   // V tile: rows are d, 128B slices
        GLL16(Vp + (size_t)((wave    ) * 8 + dr) * S_N + kt + c7 * 8, &V_lds[buf][(wave    ) * 512]);
        GLL16(Vp + (size_t)((wave + 4) * 8 + dr) * S_N + kt + c7 * 8, &V_lds[buf][(wave + 4) * 512]);
    };

    // QK^T scores for this wave's 16 q-rows vs a staged 64-row K tile.
    // C/D layout (m89): col(k) = lane&15, row(q) = (lane>>4)*4 + reg.
    auto scores = [&](const bf16* base, f32x4 (&acc)[4]) {
#pragma unroll
        for (int kb = 0; kb < 4; ++kb) {
            acc[kb] = (f32x4){0.f, 0.f, 0.f, 0.f};
#pragma unroll
            for (int ds = 0; ds < 2; ++ds) {
                bf16x8 bk = *(const bf16x8*)((const char*)base
                            + (kb * 16 + l16) * 128
                            + ((ds * 64 + lgrp * 16) ^ swx));
                acc[kb] = __builtin_amdgcn_mfma_f32_16x16x32_bf16(aq[ds], bk, acc[kb], 0, 0, 0);
            }
        }
    };

    // ---------------- Pass A: denominators (2-deep K prefetch ring) ---------
    float lsum[4] = {0.f, 0.f, 0.f, 0.f};
    stage_k(0, 0);
    for (int t = 0; t < 16; ++t) {
        if (t < 15) {
            stage_k((t + 1) * 64, (t + 1) & 1);
            // outstanding: [G(t)x2, G(t+1)x2] -> wait until only newest 2 remain
            asm volatile("s_waitcnt vmcnt(2)" ::: "memory");
        } else {
            asm volatile("s_waitcnt vmcnt(0)" ::: "memory");
        }
        __builtin_amdgcn_s_barrier();            // all waves' tile-t writes visible
        f32x4 acc[4];
        scores(&K_lds[t & 1][0], acc);
#pragma unroll
        for (int kb = 0; kb < 4; ++kb)
#pragma unroll
            for (int r = 0; r < 4; ++r) lsum[r] += __expf(acc[kb][r]);
        __builtin_amdgcn_s_barrier();            // reads done before buf reuse
    }
    float rl[4];
#pragma unroll
    for (int r = 0; r < 4; ++r) {
        float s = lsum[r];
        s += __shfl_xor(s, 1, 64);
        s += __shfl_xor(s, 2, 64);
        s += __shfl_xor(s, 4, 64);
        s += __shfl_xor(s, 8, 64);
        rl[r] = 1.0f / s;
    }

    // ---------------- Pass B: recompute, write P, accumulate O = P V --------
    f32x4 oacc[4];
#pragma unroll
    for (int db = 0; db < 4; ++db) oacc[db] = (f32x4){0.f, 0.f, 0.f, 0.f};

    const unsigned ptoff = (unsigned)(uintptr_t)(AS3 bf16*)(&Pt_lds[wave][0]);
    const int qg = qtile * 64 + wave * 16 + l16;

    stage_k(0, 0);
    stage_v(0, 0);
    for (int t = 0; t < 16; ++t) {
        const int kt = t * 64, buf = t & 1;
        if (t < 15) {
            stage_k(kt + 64, buf ^ 1);
            stage_v(kt + 64, buf ^ 1);
        }
        // issue-order outstanding at this point:
        //  t==0 : [G(0)x4, G(1)x4]                      -> vmcnt(4)
        //  1..14: [G(t)x4, Pstores(t-1)x4, G(t+1)x4]    -> vmcnt(8)
        //  t==15: [G(15)x4, Pstores(14)x4]              -> vmcnt(4)
        // (vmcnt retires in order, so waiting for G(t) never waits on the
        //  newest nt P-stores issued after it.)
        if (t == 0 || t == 15) asm volatile("s_waitcnt vmcnt(4)" ::: "memory");
        else                   asm volatile("s_waitcnt vmcnt(8)" ::: "memory");
        __builtin_amdgcn_s_barrier();

        f32x4 acc[4];
        scores(&K_lds[buf][0], acc);

        // p = exp(s)/l -> bf16; write P^T[k][q] as packed 4-q ds_write_b64
        // (lane holds r=0..3 = 4 consecutive q for k = kb*16+l16)
#pragma unroll
        for (int kb = 0; kb < 4; ++kb) {
            bf16x4 pk;
#pragma unroll
            for (int r = 0; r < 4; ++r) pk[r] = (bf16)(__expf(acc[kb][r]) * rl[r]);
            *(bf16x4*)((char*)&Pt_lds[wave][0] + (kb * 16 + l16) * 32 + lgrp * 8) = pk;
        }
        asm volatile("s_waitcnt lgkmcnt(0)" ::: "memory");  // writes done before tr reads

        const bf16* vb = &V_lds[buf][0];
#pragma unroll
        for (int ks = 0; ks < 2; ++ks) {
            // V B-fragments (swizzled row-major [d][k] reads, 2-way free)
            bf16x8 bv0 = *(const bf16x8*)((const char*)vb + (l16     ) * 128 + ((ks * 64 + lgrp * 16) ^ swx));
            bf16x8 bv1 = *(const bf16x8*)((const char*)vb + (16 + l16) * 128 + ((ks * 64 + lgrp * 16) ^ swx));
            bf16x8 bv2 = *(const bf16x8*)((const char*)vb + (32 + l16) * 128 + ((ks * 64 + lgrp * 16) ^ swx));
            bf16x8 bv3 = *(const bf16x8*)((const char*)vb + (48 + l16) * 128 + ((ks * 64 + lgrp * 16) ^ swx));

            // A-fragment via HW transpose read: lane addr selects 8B slot
            // s=(addr&127)>>3 of the 128B-aligned region; lane receives column
            // s of the region's [4][16] bf16 matrix (slot l16 -> column q=l16).
            u32x2 t0, t1;
            unsigned a = ptoff + ks * 1024 + lgrp * 256 + l16 * 8;
            asm volatile("ds_read_b64_tr_b16 %0, %2\n\t"
                         "ds_read_b64_tr_b16 %1, %2 offset:128"
                         : "=&v"(t0), "=&v"(t1) : "v"(a));
            asm volatile("s_waitcnt lgkmcnt(0)" ::: "memory");
            __builtin_amdgcn_sched_barrier(0);   // rule 18: keep MFMA below the wait

            bf16x8 ap;
            ((unsigned*)&ap)[0] = t0[0]; ((unsigned*)&ap)[1] = t0[1];
            ((unsigned*)&ap)[2] = t1[0]; ((unsigned*)&ap)[3] = t1[1];

            // Global P store: lane holds 8 contiguous k for row q=l16 -> 2x f32x4
            // NON-TEMPORAL: P is write-once, never re-read -> no L2 allocate.
            f32x4 o0, o1;
            o0[0] = __uint_as_float(t0[0] << 16);
            o0[1] = __uint_as_float(t0[0] & 0xffff0000u);
            o0[2] = __uint_as_float(t0[1] << 16);
            o0[3] = __uint_as_float(t0[1] & 0xffff0000u);
            o1[0] = __uint_as_float(t1[0] << 16);
            o1[1] = __uint_as_float(t1[0] & 0xffff0000u);
            o1[2] = __uint_as_float(t1[1] << 16);
            o1[3] = __uint_as_float(t1[1] & 0xffff0000u);
            float* pp = Pp + (size_t)qg * S_N + kt + ks * 32 + lgrp * 8;
            __builtin_nontemporal_store(o0, (f32x4*)pp);
            __builtin_nontemporal_store(o1, (f32x4*)(pp + 4));

            oacc[0] = __builtin_amdgcn_mfma_f32_16x16x32_bf16(ap, bv0, oacc[0], 0, 0, 0);
            oacc[1] = __builtin_amdgcn_mfma_f32_16x16x32_bf16(ap, bv1, oacc[1], 0, 0, 0);
            oacc[2] = __builtin_amdgcn_mfma_f32_16x16x32_bf16(ap, bv2, oacc[2], 0, 0, 0);
            oacc[3] = __builtin_amdgcn_mfma_f32_16x16x32_bf16(ap, bv3, oacc[3], 0, 0, 0);
        }
        __builtin_amdgcn_s_barrier();            // reads done before buf reuse
    }

    const int qb0 = qtile * 64 + wave * 16 + lgrp * 4;
#pragma unroll
    for (int db = 0; db < 4; ++db)
#pragma unroll
        for (int r = 0; r < 4; ++r)
            __builtin_nontemporal_store(oacc[db][r],
                &Op[(size_t)(qb0 + r) * D_N + db * 16 + l16]);
}

// ============================================================================
// Round-1 fallback (fp32 inputs, no workspace) — used only if ws too small.
// ============================================================================
__global__ __launch_bounds__(256)
void sdpa_fused(const float* __restrict__ Qg, const float* __restrict__ Kg,
                const float* __restrict__ Vg, float* __restrict__ Og,
                float* __restrict__ Pg)
{
    constexpr int LDP = 72;
    __shared__ bf16 K_lds [64][LDP];
    __shared__ bf16 Vt_lds[64][LDP];
    __shared__ bf16 P_lds [4][16][LDP];

    const int qtile = blockIdx.x;
    const int bh    = blockIdx.y;
    const int tid   = threadIdx.x;
    const int wave  = tid >> 6;
    const int lane  = tid & 63;
    const int l16   = lane & 15;
    const int lgrp  = lane >> 4;

    const float* Qp = Qg + (size_t)bh * S_N * D_N;
    const float* Kp = Kg + (size_t)bh * S_N * D_N;
    const float* Vp = Vg + (size_t)bh * S_N * D_N;
    float* Op = Og + (size_t)bh * S_N * D_N;
    float* Pp = Pg + (size_t)bh * S_N * S_N;

    const int qrow = qtile * 64 + wave * 16 + l16;
    bf16x8 aq[2];
#pragma unroll
    for (int ds = 0; ds < 2; ++ds) {
        const float* src = Qp + qrow * D_N + ds * 32 + lgrp * 8;
        float4 f0 = *(const float4*)(src);
        float4 f1 = *(const float4*)(src + 4);
        aq[ds][0] = (bf16)(f0.x * 0.125f); aq[ds][1] = (bf16)(f0.y * 0.125f);
        aq[ds][2] = (bf16)(f0.z * 0.125f); aq[ds][3] = (bf16)(f0.w * 0.125f);
        aq[ds][4] = (bf16)(f1.x * 0.125f); aq[ds][5] = (bf16)(f1.y * 0.125f);
        aq[ds][6] = (bf16)(f1.z * 0.125f); aq[ds][7] = (bf16)(f1.w * 0.125f);
    }

    auto stage_k = [&](int kt) {
#pragma unroll
        for (int i = 0; i < 4; ++i) {
            int slot = tid + i * 256;
            int row = slot >> 4, c4 = slot & 15;
            float4 f = *(const float4*)(Kp + (kt + row) * D_N + c4 * 4);
            bf16x4 pk = {(bf16)f.x, (bf16)f.y, (bf16)f.z, (bf16)f.w};
            *(bf16x4*)&K_lds[row][c4 * 4] = pk;
        }
    };
    auto stage_v = [&](int kt) {
#pragma unroll
        for (int i = 0; i < 4; ++i) {
            int slot = tid + i * 256;
            int row = slot >> 4, c4 = slot & 15;
            float4 f = *(const float4*)(Vp + (kt + row) * D_N + c4 * 4);
            Vt_lds[c4 * 4 + 0][row] = (bf16)f.x;
            Vt_lds[c4 * 4 + 1][row] = (bf16)f.y;
            Vt_lds[c4 * 4 + 2][row] = (bf16)f.z;
            Vt_lds[c4 * 4 + 3][row] = (bf16)f.w;
        }
    };
    auto compute_scores = [&](f32x4 (&acc)[4]) {
#pragma unroll
        for (int kb = 0; kb < 4; ++kb) {
            acc[kb] = (f32x4){0.f, 0.f, 0.f, 0.f};
#pragma unroll
            for (int ds = 0; ds < 2; ++ds) {
                bf16x8 bk = *(const bf16x8*)&K_lds[kb * 16 + l16][ds * 32 + lgrp * 8];
                acc[kb] = __builtin_amdgcn_mfma_f32_16x16x32_bf16(aq[ds], bk, acc[kb], 0, 0, 0);
            }
        }
    };

    float lsum[4] = {0.f, 0.f, 0.f, 0.f};
    for (int kt = 0; kt < S_N; kt += 64) {
        __syncthreads();
        stage_k(kt);
        __syncthreads();
        f32x4 acc[4];
        compute_scores(acc);
#pragma unroll
        for (int kb = 0; kb < 4; ++kb)
#pragma unroll
            for (int r = 0; r < 4; ++r) lsum[r] += __expf(acc[kb][r]);
    }
    float rl[4];
#pragma unroll
    for (int r = 0; r < 4; ++r) {
        float s = lsum[r];
        s += __shfl_xor(s, 1, 64);
        s += __shfl_xor(s, 2, 64);
        s += __shfl_xor(s, 4, 64);
        s += __shfl_xor(s, 8, 64);
        rl[r] = 1.0f / s;
    }

    f32x4 oacc[4];
#pragma unroll
    for (int db = 0; db < 4; ++db) oacc[db] = (f32x4){0.f, 0.f, 0.f, 0.f};
    const int qb0 = qtile * 64 + wave * 16 + lgrp * 4;

    for (int kt = 0; kt < S_N; kt += 64) {
        __syncthreads();
        stage_k(kt);
        stage_v(kt);
        __syncthreads();

        f32x4 acc[4];
        compute_scores(acc);
#pragma unroll
        for (int kb = 0; kb < 4; ++kb) {
#pragma unroll
            for (int r = 0; r < 4; ++r) {
                float p = __expf(acc[kb][r]) * rl[r];
                Pp[(size_t)(qb0 + r) * S_N + (kt + kb * 16 + l16)] = p;
                P_lds[wave][lgrp * 4 + r][kb * 16 + l16] = (bf16)p;
            }
        }
#pragma unroll
        for (int ks = 0; ks < 2; ++ks) {
            bf16x8 ap = *(const bf16x8*)&P_lds[wave][l16][ks * 32 + lgrp * 8];
#pragma unroll
            for (int db = 0; db < 4; ++db) {
                bf16x8 bv = *(const bf16x8*)&Vt_lds[db * 16 + l16][ks * 32 + lgrp * 8];
                oacc[db] = __builtin_amdgcn_mfma_f32_16x16x32_bf16(ap, bv, oacc[db], 0, 0, 0);
            }
        }
    }

#pragma unroll
    for (int db = 0; db < 4; ++db)
#pragma unroll
        for (int r = 0; r < 4; ++r)
            Op[(size_t)(qb0 + r) * D_N + db * 16 + l16] = oacc[db][r];
}

extern "C" void kernel_launch(void* const* d_in, const int* in_sizes, int n_in,
                              void* d_out, int out_size, void* d_ws, size_t ws_size,
                              hipStream_t stream) {
    const float* Q = (const float*)d_in[0];
    const float* K = (const float*)d_in[1];
    const float* V = (const float*)d_in[2];
    float* Out = (float*)d_out;                       // [4,16,1024,64]
    float* P   = (float*)d_out + (size_t)NELEM;       // [4,16,1024,1024]

    const size_t need = (size_t)NELEM * 2 * 3;        // Qb + Kb + Vt, bf16
    if (ws_size >= need) {
        bf16* Qb = (bf16*)d_ws;
        bf16* Kb = Qb + NELEM;
        bf16* Vt = Kb + NELEM;
        prep_qk<<<dim3(2 * NELEM / 8 / 256), dim3(256), 0, stream>>>(Q, K, Qb, Kb);
        prep_v<<<dim3(64 * 128 / 4), dim3(256), 0, stream>>>(V, Vt);
        sdpa_main<<<dim3(1024), dim3(256), 0, stream>>>(Qb, Kb, Vt, Out, P);
    } else {
        sdpa_fused<<<dim3(16, 64), dim3(256), 0, stream>>>(Q, K, V, Out, P);
    }
}

// Round 9
// 96.238 us; speedup vs baseline: 1.8075x; 1.8075x over previous
//
#include <hip/hip_runtime.h>
#include <hip/hip_bf16.h>

// Problem constants (fixed by the reference): B=4, H=16, S=1024, D=64.
#define B_N 4
#define H_N 16
#define S_N 1024
#define D_N 64
#define NELEM (B_N * H_N * S_N * D_N)   // 4194304 elements per tensor

typedef __bf16 bf16;
typedef bf16  bf16x4 __attribute__((ext_vector_type(4)));
typedef bf16  bf16x8 __attribute__((ext_vector_type(8)));
typedef float f32x4  __attribute__((ext_vector_type(4)));
typedef unsigned int u32x2 __attribute__((ext_vector_type(2)));

#define AS1 __attribute__((address_space(1)))
#define AS3 __attribute__((address_space(3)))
// global->LDS DMA, 16B per lane; LDS dest = wave-uniform base + lane*16 (m104)
#define GLL16(gp, lp) __builtin_amdgcn_global_load_lds((const AS1 void*)(gp), (AS3 void*)(lp), 16, 0, 0)

// ============================================================================
// Prep (one kernel): fp32 -> bf16 swizzled copies of K and V into d_ws.
//  Kb[bh][k][d]  16B slots within each 128B row XORed by (k&7)
//  Vt[bh][d][k]  transposed; within each 64-k chunk, slots XORed by (d&7)
// Q is NOT prepped — the main kernel reads fp32 Q directly (16KB/block, once).
// ============================================================================
__global__ __launch_bounds__(256)
void prep_kv(const float* __restrict__ K, const float* __restrict__ V,
             bf16* __restrict__ Kb, bf16* __restrict__ Vt)
{
    const int b = blockIdx.x;
    if (b < 2048) {                        // ---- K: swizzled bf16 copy ----
        int t = b * 256 + threadIdx.x;     // 8 elems per thread
        int row = t >> 3, sub = t & 7;     // row = bh*S + k; sub = 16B slot
        const float* src = K + (size_t)row * 64 + sub * 8;
        float4 f0 = *(const float4*)src;
        float4 f1 = *(const float4*)(src + 4);
        bf16x8 o;
        o[0] = (bf16)f0.x; o[1] = (bf16)f0.y; o[2] = (bf16)f0.z; o[3] = (bf16)f0.w;
        o[4] = (bf16)f1.x; o[5] = (bf16)f1.y; o[6] = (bf16)f1.z; o[7] = (bf16)f1.w;
        int slot = sub ^ (row & 7);
        *(bf16x8*)(Kb + (size_t)row * 64 + slot * 8) = o;
    } else {                               // ---- V: transpose + swizzle ----
        int wid  = (b - 2048) * 4 + (threadIdx.x >> 6);
        int lane = threadIdx.x & 63;       // lane = d
        int bh = wid >> 7, chunk = wid & 127;   // 128 chunks of 8 k-rows
        const float* src = V + (size_t)bh * S_N * D_N + (size_t)chunk * 8 * 64 + lane;
        bf16x8 o;
#pragma unroll
        for (int j = 0; j < 8; ++j) o[j] = (bf16)src[j * 64];
        int slot = (chunk & 7) ^ (lane & 7);
        bf16* dst = Vt + (size_t)bh * D_N * S_N + (size_t)lane * S_N
                       + (chunk >> 3) * 64 + slot * 8;
        *(bf16x8*)dst = o;
    }
}

// ============================================================================
// Main fused kernel: 1 block = 64 q-rows (4 waves x 16), two passes over K.
// Round 9: round-3 compute bodies (verified PASS @102µs) + 1-barrier/iter
// software pipeline: issue next tile's GLL16s into the other buffer, compute
// current tile, then ONE __syncthreads whose vmcnt(0) drain doubles as the
// staging-completion guarantee (staging latency hides under exp+PV).
// ============================================================================
__global__ __launch_bounds__(256)
void sdpa_main(const float* __restrict__ Qf, const bf16* __restrict__ Kb,
               const bf16* __restrict__ Vt, float* __restrict__ Og,
               float* __restrict__ Pg)
{
    __shared__ __attribute__((aligned(128))) bf16 K_lds[2][4096];   // 16KB
    __shared__ __attribute__((aligned(128))) bf16 V_lds[2][4096];   // 16KB
    __shared__ __attribute__((aligned(128))) bf16 Pt_lds[4][1024];  // 8KB

    // XCD-bijective swizzle: 16 q-tiles of each bh land on one XCD (nwg=1024%8==0)
    const int bid = blockIdx.x;
    const int swz = (bid & 7) * 128 + (bid >> 3);
    const int bh = swz >> 4, qtile = swz & 15;

    const int tid = threadIdx.x;
    const int wave = tid >> 6, lane = tid & 63;
    const int l16 = lane & 15, lgrp = lane >> 4;
    const int swx = (l16 & 7) << 4;     // byte XOR for swizzled LDS reads

    const float* Qp = Qf + (size_t)bh * S_N * D_N;
    const bf16* Kp = Kb + (size_t)bh * S_N * D_N;
    const bf16* Vp = Vt + (size_t)bh * D_N * S_N;
    float* Op = Og + (size_t)bh * S_N * D_N;
    float* Pp = Pg + (size_t)bh * S_N * S_N;

    // Q A-fragments from fp32, scaled by 1/sqrt(64): a[j]=Q[q=l16][k=lgrp*8+j]
    const int qrow = qtile * 64 + wave * 16 + l16;
    bf16x8 aq[2];
#pragma unroll
    for (int ds = 0; ds < 2; ++ds) {
        const float* src = Qp + (size_t)qrow * 64 + ds * 32 + lgrp * 8;
        float4 f0 = *(const float4*)src;
        float4 f1 = *(const float4*)(src + 4);
        aq[ds][0] = (bf16)(f0.x * 0.125f); aq[ds][1] = (bf16)(f0.y * 0.125f);
        aq[ds][2] = (bf16)(f0.z * 0.125f); aq[ds][3] = (bf16)(f0.w * 0.125f);
        aq[ds][4] = (bf16)(f1.x * 0.125f); aq[ds][5] = (bf16)(f1.y * 0.125f);
        aq[ds][6] = (bf16)(f1.z * 0.125f); aq[ds][7] = (bf16)(f1.w * 0.125f);
    }

    // Staging: one 64x64 bf16 tile = 8KB = 2 GLL16 per wave (4 waves)
    auto stage_k = [&](int kt, bf16* dst) {
        const bf16* gk = Kp + (size_t)kt * 64;
        GLL16(gk + (wave    ) * 512 + lane * 8, dst + (wave    ) * 512);
        GLL16(gk + (wave + 4) * 512 + lane * 8, dst + (wave + 4) * 512);
    };
    // 128-k double tile (16KB contiguous) into two 8KB buffers
    auto stage_k2 = [&](int kt, bf16* dst0, bf16* dst1) {
        const bf16* gk = Kp + (size_t)kt * 64;
        GLL16(gk + (wave     ) * 512 + lane * 8, dst0 + (wave    ) * 512);
        GLL16(gk + (wave + 4 ) * 512 + lane * 8, dst0 + (wave + 4) * 512);
        GLL16(gk + (wave + 8 ) * 512 + lane * 8, dst1 + (wave    ) * 512);
        GLL16(gk + (wave + 12) * 512 + lane * 8, dst1 + (wave + 4) * 512);
    };
    auto stage_v = [&](int kt, bf16* dst) {
        const int dr = lane >> 3, c7 = lane & 7;   // rows are d, 128B slices
        GLL16(Vp + (size_t)((wave    ) * 8 + dr) * S_N + kt + c7 * 8, dst + (wave    ) * 512);
        GLL16(Vp + (size_t)((wave + 4) * 8 + dr) * S_N + kt + c7 * 8, dst + (wave + 4) * 512);
    };

    // QK^T scores for this wave's 16 q-rows vs a staged 64-row K tile.
    // C/D layout (m89): col(k) = lane&15, row(q) = (lane>>4)*4 + reg.
    auto scores = [&](const bf16* base, f32x4 (&acc)[4]) {
#pragma unroll
        for (int kb = 0; kb < 4; ++kb) {
            acc[kb] = (f32x4){0.f, 0.f, 0.f, 0.f};
#pragma unroll
            for (int ds = 0; ds < 2; ++ds) {
                bf16x8 bk = *(const bf16x8*)((const char*)base
                            + (kb * 16 + l16) * 128
                            + ((ds * 64 + lgrp * 16) ^ swx));
                acc[kb] = __builtin_amdgcn_mfma_f32_16x16x32_bf16(aq[ds], bk, acc[kb], 0, 0, 0);
            }
        }
    };

    // -------- Pass A: denominators. 128 k per iter, 1 barrier per iter. -----
    // Buffers alternate: even c computes K_lds pair, odd c computes V_lds pair;
    // prefetch for c+1 goes into the pair not being read. The __syncthreads
    // vmcnt(0) drain at iter end guarantees the prefetched pair is complete.
    float lsum[4] = {0.f, 0.f, 0.f, 0.f};
    stage_k2(0, &K_lds[0][0], &K_lds[1][0]);
    __syncthreads();
    for (int c = 0; c < 8; ++c) {
        const bf16* b0 = (c & 1) ? &V_lds[0][0] : &K_lds[0][0];
        const bf16* b1 = (c & 1) ? &V_lds[1][0] : &K_lds[1][0];
        bf16* n0 = (c & 1) ? &K_lds[0][0] : &V_lds[0][0];
        bf16* n1 = (c & 1) ? &K_lds[1][0] : &V_lds[1][0];
        if (c < 7) stage_k2((c + 1) * 128, n0, n1);
        f32x4 acc[4];
        scores(b0, acc);
#pragma unroll
        for (int kb = 0; kb < 4; ++kb)
#pragma unroll
            for (int r = 0; r < 4; ++r) lsum[r] += __expf(acc[kb][r]);
        scores(b1, acc);
#pragma unroll
        for (int kb = 0; kb < 4; ++kb)
#pragma unroll
            for (int r = 0; r < 4; ++r) lsum[r] += __expf(acc[kb][r]);
        __syncthreads();
    }
    float rl[4];
#pragma unroll
    for (int r = 0; r < 4; ++r) {
        float s = lsum[r];
        s += __shfl_xor(s, 1, 64);
        s += __shfl_xor(s, 2, 64);
        s += __shfl_xor(s, 4, 64);
        s += __shfl_xor(s, 8, 64);
        rl[r] = 1.0f / s;
    }

    // ---- Pass B: recompute, write P, accumulate O = P V. 1 barrier/iter. ---
    f32x4 oacc[4];
#pragma unroll
    for (int db = 0; db < 4; ++db) oacc[db] = (f32x4){0.f, 0.f, 0.f, 0.f};

    const unsigned ptoff = (unsigned)(uintptr_t)(AS3 bf16*)(&Pt_lds[wave][0]);
    const int qg = qtile * 64 + wave * 16 + l16;

    stage_k(0, &K_lds[0][0]);
    stage_v(0, &V_lds[0][0]);
    __syncthreads();
    for (int t = 0; t < 16; ++t) {
        const int kt = t * 64, buf = t & 1;

        f32x4 acc[4];
        scores(&K_lds[buf][0], acc);

        // Prefetch t+1 into the other buffer; completion guaranteed by the
        // __syncthreads drain at iter end; latency hides under exp+PV below.
        if (t < 15) {
            stage_k(kt + 64, &K_lds[buf ^ 1][0]);
            stage_v(kt + 64, &V_lds[buf ^ 1][0]);
        }

        // p = exp(s)/l -> bf16; write P^T[k][q] as packed 4-q ds_write_b64
        // (lane holds r=0..3 = 4 consecutive q for k = kb*16+l16)
#pragma unroll
        for (int kb = 0; kb < 4; ++kb) {
            bf16x4 pk;
#pragma unroll
            for (int r = 0; r < 4; ++r) pk[r] = (bf16)(__expf(acc[kb][r]) * rl[r]);
            *(bf16x4*)((char*)&Pt_lds[wave][0] + (kb * 16 + l16) * 32 + lgrp * 8) = pk;
        }
        asm volatile("s_waitcnt lgkmcnt(0)" ::: "memory");  // writes done before tr reads

        const bf16* vb = &V_lds[buf][0];
#pragma unroll
        for (int ks = 0; ks < 2; ++ks) {
            // V B-fragments (swizzled row-major [d][k] reads, 2-way free)
            bf16x8 bv0 = *(const bf16x8*)((const char*)vb + (l16     ) * 128 + ((ks * 64 + lgrp * 16) ^ swx));
            bf16x8 bv1 = *(const bf16x8*)((const char*)vb + (16 + l16) * 128 + ((ks * 64 + lgrp * 16) ^ swx));
            bf16x8 bv2 = *(const bf16x8*)((const char*)vb + (32 + l16) * 128 + ((ks * 64 + lgrp * 16) ^ swx));
            bf16x8 bv3 = *(const bf16x8*)((const char*)vb + (48 + l16) * 128 + ((ks * 64 + lgrp * 16) ^ swx));

            // PV A-fragment via HW transpose read. Model (r2/r3/r6/r8 A/Bs):
            // region (128B) selection is uniform per 16-lane group (here via
            // lgrp only); per-lane addr slot (addr&127)>>3 picks the column.
            // Slot l16 -> column q=l16 of the region's [4k][16q] matrix.
            u32x2 t0, t1;
            unsigned a = ptoff + ks * 1024 + lgrp * 256 + l16 * 8;
            asm volatile("ds_read_b64_tr_b16 %0, %2\n\t"
                         "ds_read_b64_tr_b16 %1, %2 offset:128"
                         : "=&v"(t0), "=&v"(t1) : "v"(a));
            asm volatile("s_waitcnt lgkmcnt(0)" ::: "memory");
            __builtin_amdgcn_sched_barrier(0);   // rule 18: keep MFMA below the wait

            bf16x8 ap;
            ((unsigned*)&ap)[0] = t0[0]; ((unsigned*)&ap)[1] = t0[1];
            ((unsigned*)&ap)[2] = t1[0]; ((unsigned*)&ap)[3] = t1[1];

            // Global P store: lane holds 8 contiguous k for row q=l16 -> 2x f32x4
            // (L2 merges the per-row halves via byte-enables; full lines reach HBM)
            float4 o0, o1;
            o0.x = __uint_as_float(t0[0] << 16);
            o0.y = __uint_as_float(t0[0] & 0xffff0000u);
            o0.z = __uint_as_float(t0[1] << 16);
            o0.w = __uint_as_float(t0[1] & 0xffff0000u);
            o1.x = __uint_as_float(t1[0] << 16);
            o1.y = __uint_as_float(t1[0] & 0xffff0000u);
            o1.z = __uint_as_float(t1[1] << 16);
            o1.w = __uint_as_float(t1[1] & 0xffff0000u);
            float* pp = Pp + (size_t)qg * S_N + kt + ks * 32 + lgrp * 8;
            *(float4*)pp = o0;
            *(float4*)(pp + 4) = o1;

            oacc[0] = __builtin_amdgcn_mfma_f32_16x16x32_bf16(ap, bv0, oacc[0], 0, 0, 0);
            oacc[1] = __builtin_amdgcn_mfma_f32_16x16x32_bf16(ap, bv1, oacc[1], 0, 0, 0);
            oacc[2] = __builtin_amdgcn_mfma_f32_16x16x32_bf16(ap, bv2, oacc[2], 0, 0, 0);
            oacc[3] = __builtin_amdgcn_mfma_f32_16x16x32_bf16(ap, bv3, oacc[3], 0, 0, 0);
        }
        __syncthreads();   // joins waves AND drains vmcnt -> prefetch complete
    }

    const int qb0 = qtile * 64 + wave * 16 + lgrp * 4;
#pragma unroll
    for (int db = 0; db < 4; ++db)
#pragma unroll
        for (int r = 0; r < 4; ++r)
            Op[(size_t)(qb0 + r) * D_N + db * 16 + l16] = oacc[db][r];
}

// ============================================================================
// Round-1 fallback (fp32 inputs, no workspace) — used only if ws too small.
// ============================================================================
__global__ __launch_bounds__(256)
void sdpa_fused(const float* __restrict__ Qg, const float* __restrict__ Kg,
                const float* __restrict__ Vg, float* __restrict__ Og,
                float* __restrict__ Pg)
{
    constexpr int LDP = 72;
    __shared__ bf16 K_lds [64][LDP];
    __shared__ bf16 Vt_lds[64][LDP];
    __shared__ bf16 P_lds [4][16][LDP];

    const int qtile = blockIdx.x;
    const int bh    = blockIdx.y;
    const int tid   = threadIdx.x;
    const int wave  = tid >> 6;
    const int lane  = tid & 63;
    const int l16   = lane & 15;
    const int lgrp  = lane >> 4;

    const float* Qp = Qg + (size_t)bh * S_N * D_N;
    const float* Kp = Kg + (size_t)bh * S_N * D_N;
    const float* Vp = Vg + (size_t)bh * S_N * D_N;
    float* Op = Og + (size_t)bh * S_N * D_N;
    float* Pp = Pg + (size_t)bh * S_N * S_N;

    const int qrow = qtile * 64 + wave * 16 + l16;
    bf16x8 aq[2];
#pragma unroll
    for (int ds = 0; ds < 2; ++ds) {
        const float* src = Qp + qrow * D_N + ds * 32 + lgrp * 8;
        float4 f0 = *(const float4*)(src);
        float4 f1 = *(const float4*)(src + 4);
        aq[ds][0] = (bf16)(f0.x * 0.125f); aq[ds][1] = (bf16)(f0.y * 0.125f);
        aq[ds][2] = (bf16)(f0.z * 0.125f); aq[ds][3] = (bf16)(f0.w * 0.125f);
        aq[ds][4] = (bf16)(f1.x * 0.125f); aq[ds][5] = (bf16)(f1.y * 0.125f);
        aq[ds][6] = (bf16)(f1.z * 0.125f); aq[ds][7] = (bf16)(f1.w * 0.125f);
    }

    auto stage_k = [&](int kt) {
#pragma unroll
        for (int i = 0; i < 4; ++i) {
            int slot = tid + i * 256;
            int row = slot >> 4, c4 = slot & 15;
            float4 f = *(const float4*)(Kp + (kt + row) * D_N + c4 * 4);
            bf16x4 pk = {(bf16)f.x, (bf16)f.y, (bf16)f.z, (bf16)f.w};
            *(bf16x4*)&K_lds[row][c4 * 4] = pk;
        }
    };
    auto stage_v = [&](int kt) {
#pragma unroll
        for (int i = 0; i < 4; ++i) {
            int slot = tid + i * 256;
            int row = slot >> 4, c4 = slot & 15;
            float4 f = *(const float4*)(Vp + (kt + row) * D_N + c4 * 4);
            Vt_lds[c4 * 4 + 0][row] = (bf16)f.x;
            Vt_lds[c4 * 4 + 1][row] = (bf16)f.y;
            Vt_lds[c4 * 4 + 2][row] = (bf16)f.z;
            Vt_lds[c4 * 4 + 3][row] = (bf16)f.w;
        }
    };
    auto compute_scores = [&](f32x4 (&acc)[4]) {
#pragma unroll
        for (int kb = 0; kb < 4; ++kb) {
            acc[kb] = (f32x4){0.f, 0.f, 0.f, 0.f};
#pragma unroll
            for (int ds = 0; ds < 2; ++ds) {
                bf16x8 bk = *(const bf16x8*)&K_lds[kb * 16 + l16][ds * 32 + lgrp * 8];
                acc[kb] = __builtin_amdgcn_mfma_f32_16x16x32_bf16(aq[ds], bk, acc[kb], 0, 0, 0);
            }
        }
    };

    float lsum[4] = {0.f, 0.f, 0.f, 0.f};
    for (int kt = 0; kt < S_N; kt += 64) {
        __syncthreads();
        stage_k(kt);
        __syncthreads();
        f32x4 acc[4];
        compute_scores(acc);
#pragma unroll
        for (int kb = 0; kb < 4; ++kb)
#pragma unroll
            for (int r = 0; r < 4; ++r) lsum[r] += __expf(acc[kb][r]);
    }
    float rl[4];
#pragma unroll
    for (int r = 0; r < 4; ++r) {
        float s = lsum[r];
        s += __shfl_xor(s, 1, 64);
        s += __shfl_xor(s, 2, 64);
        s += __shfl_xor(s, 4, 64);
        s += __shfl_xor(s, 8, 64);
        rl[r] = 1.0f / s;
    }

    f32x4 oacc[4];
#pragma unroll
    for (int db = 0; db < 4; ++db) oacc[db] = (f32x4){0.f, 0.f, 0.f, 0.f};
    const int qb0 = qtile * 64 + wave * 16 + lgrp * 4;

    for (int kt = 0; kt < S_N; kt += 64) {
        __syncthreads();
        stage_k(kt);
        stage_v(kt);
        __syncthreads();

        f32x4 acc[4];
        compute_scores(acc);
#pragma unroll
        for (int kb = 0; kb < 4; ++kb) {
#pragma unroll
            for (int r = 0; r < 4; ++r) {
                float p = __expf(acc[kb][r]) * rl[r];
                Pp[(size_t)(qb0 + r) * S_N + (kt + kb * 16 + l16)] = p;
                P_lds[wave][lgrp * 4 + r][kb * 16 + l16] = (bf16)p;
            }
        }
#pragma unroll
        for (int ks = 0; ks < 2; ++ks) {
            bf16x8 ap = *(const bf16x8*)&P_lds[wave][l16][ks * 32 + lgrp * 8];
#pragma unroll
            for (int db = 0; db < 4; ++db) {
                bf16x8 bv = *(const bf16x8*)&Vt_lds[db * 16 + l16][ks * 32 + lgrp * 8];
                oacc[db] = __builtin_amdgcn_mfma_f32_16x16x32_bf16(ap, bv, oacc[db], 0, 0, 0);
            }
        }
    }

#pragma unroll
    for (int db = 0; db < 4; ++db)
#pragma unroll
        for (int r = 0; r < 4; ++r)
            Op[(size_t)(qb0 + r) * D_N + db * 16 + l16] = oacc[db][r];
}

extern "C" void kernel_launch(void* const* d_in, const int* in_sizes, int n_in,
                              void* d_out, int out_size, void* d_ws, size_t ws_size,
                              hipStream_t stream) {
    const float* Q = (const float*)d_in[0];
    const float* K = (const float*)d_in[1];
    const float* V = (const float*)d_in[2];
    float* Out = (float*)d_out;                       // [4,16,1024,64]
    float* P   = (float*)d_out + (size_t)NELEM;       // [4,16,1024,1024]

    const size_t need = (size_t)NELEM * 2 * 2;        // Kb + Vt, bf16
    if (ws_size >= need) {
        bf16* Kb = (bf16*)d_ws;
        bf16* Vt = Kb + NELEM;
        prep_kv<<<dim3(4096), dim3(256), 0, stream>>>(K, V, Kb, Vt);
        sdpa_main<<<dim3(1024), dim3(256), 0, stream>>>(Q, Kb, Vt, Out, P);
    } else {
        sdpa_fused<<<dim3(16, 64), dim3(256), 0, stream>>>(Q, K, V, Out, P);
    }
}